// Round 1
// baseline (2877.526 us; speedup 1.0000x reference)
//
#include <hip/hip_runtime.h>

// Problem constants (match reference)
#define BATCH 2048
#define DM    256
#define NFEAT 32768
#define NBLK  8
#define ALPHA_C   0.99f
#define EPS_CTRL  3e-4f
#define TARGET_L0 100.0f

// Tiling
#define BT 32          // batch rows per workgroup
#define FT 64          // feature subtile
#define FC 2048        // features per chunk (NFEAT/FC = 16 chunks)

// Workspace layout (float offsets)
#define WS_RA    0
#define WS_SCALE 1
#define WS_L0    2     // as unsigned
#define WS_L1    4     // 8 floats
#define WS_ERR   16    // 8 floats
#define WS_WDN   256   // 32768 floats
#define WS_PREDS (WS_WDN + NFEAT)
#define PREDS_FLOATS ((size_t)NBLK * BATCH * DM)
#define WS_TOTAL_BYTES ((WS_PREDS + PREDS_FLOATS) * sizeof(float))

// ---------------- small kernels ----------------

// mean row norm of x: one wave per row (256 f32 = 4/lane)
__global__ __launch_bounds__(256) void k_rownorm(const float* __restrict__ x,
                                                 float* ws) {
    const int wave = threadIdx.x >> 6, lane = threadIdx.x & 63;
    const int row = blockIdx.x * 4 + wave;
    const float4 v = *reinterpret_cast<const float4*>(x + (size_t)row * DM + lane * 4);
    float s = v.x * v.x + v.y * v.y + v.z * v.z + v.w * v.w;
    #pragma unroll
    for (int o = 32; o; o >>= 1) s += __shfl_xor(s, o);
    if (lane == 0) atomicAdd(&ws[WS_RA], sqrtf(s));
}

// W_dec row norms: one wave per feature row
__global__ __launch_bounds__(256) void k_wdn(const float* __restrict__ Wd,
                                             float* ws) {
    const int wave = threadIdx.x >> 6, lane = threadIdx.x & 63;
    const int f = blockIdx.x * 4 + wave;
    const float4 v = *reinterpret_cast<const float4*>(Wd + (size_t)f * DM + lane * 4);
    float s = v.x * v.x + v.y * v.y + v.z * v.z + v.w * v.w;
    #pragma unroll
    for (int o = 32; o; o >>= 1) s += __shfl_xor(s, o);
    if (lane == 0) ws[WS_WDN + f] = sqrtf(s);
}

__global__ void k_scale(const float* __restrict__ ravg, float* ws) {
    float ra = ALPHA_C * ravg[0] + (1.0f - ALPHA_C) * (ws[WS_RA] / (float)BATCH);
    ws[WS_SCALE] = 16.0f / ra;   // sqrt(256) = 16
}

// ---------------- main fused kernel ----------------
// grid: (NFEAT/FC, BATCH/BT), block 256.
// Each workgroup: stages x-tile (scaled) in LDS, sweeps its feature chunk in
// order: phase A computes acts subtile (+log-L1, +L0), phase B accumulates the
// running decode pred[BT] per thread (thread t owns output dim t), flushing to
// per-block partial buffers at segment boundaries.
__global__ __launch_bounds__(256) void k_main(const float* __restrict__ x,
                                              const float* __restrict__ We,
                                              const float* __restrict__ be,
                                              const float* __restrict__ Wd,
                                              const int* __restrict__ seg,
                                              float* ws) {
    __shared__ float xs[BT][DM];      // 32 KB
    __shared__ float acts[BT][FT];    // 8 KB
    __shared__ int   segs[FT];
    __shared__ float lds_l1[NBLK];
    __shared__ unsigned lds_l0;

    const int t = threadIdx.x;
    const int chunk = blockIdx.x;     // 0..15
    const int btile = blockIdx.y;     // 0..63
    const int b0 = btile * BT;
    const int f0 = chunk * FC;
    const float scale = ws[WS_SCALE];

    if (t < NBLK) lds_l1[t] = 0.0f;
    if (t == 0) lds_l0 = 0u;

    // stage x * scale (coalesced, conflict-free)
    #pragma unroll
    for (int i = 0; i < BT; ++i)
        xs[i][t] = x[(size_t)(b0 + i) * DM + t] * scale;

    float pred[BT];
    #pragma unroll
    for (int i = 0; i < BT; ++i) pred[i] = 0.0f;

    int cur_seg = seg[f0];
    float l1_acc = 0.0f;
    int my_seg = -1;
    unsigned l0_cnt = 0u;

    float* preds = ws + WS_PREDS;
    const int fl = t & 63;            // feature lane within subtile
    const int rg = t >> 6;            // row group (wave id), 8 rows each

    auto flush = [&](int sgto) {
        float* p = preds + (size_t)sgto * BATCH * DM + (size_t)b0 * DM + t;
        #pragma unroll
        for (int b = 0; b < BT; ++b) { atomicAdd(p + (size_t)b * DM, pred[b]); pred[b] = 0.0f; }
    };

    for (int sub = 0; sub < FC / FT; ++sub) {
        const int fs = f0 + sub * FT;
        const int f = fs + fl;
        if (t < FT) segs[t] = seg[fs + t];
        __syncthreads();   // also separates prev phase-B reads from acts writes

        // ---- phase A: acts[rg*8 + r][fl] for r in 0..7
        float acc[8];
        #pragma unroll
        for (int r = 0; r < 8; ++r) acc[r] = 0.0f;
        const float* wc = We + (size_t)f;
        #pragma unroll 4
        for (int k = 0; k < DM; k += 4) {
            const float w0 = wc[(size_t)(k + 0) * NFEAT];
            const float w1 = wc[(size_t)(k + 1) * NFEAT];
            const float w2 = wc[(size_t)(k + 2) * NFEAT];
            const float w3 = wc[(size_t)(k + 3) * NFEAT];
            #pragma unroll
            for (int r = 0; r < 8; ++r) {
                const float4 xv = *reinterpret_cast<const float4*>(&xs[rg * 8 + r][k]);
                acc[r] += xv.x * w0 + xv.y * w1 + xv.z * w2 + xv.w * w3;
            }
        }
        const float bias = be[f];
        const float wdn = ws[WS_WDN + f];
        const int sg = segs[fl];
        if (sg != my_seg) {
            if (my_seg >= 0) atomicAdd(&lds_l1[my_seg], l1_acc);
            l1_acc = 0.0f; my_seg = sg;
        }
        #pragma unroll
        for (int r = 0; r < 8; ++r) {
            float a = acc[r] + bias;
            a = a > 0.0f ? a : 0.0f;
            acts[rg * 8 + r][fl] = a;
            l0_cnt += (a > 0.0f) ? 1u : 0u;
            l1_acc += __logf(fmaf(a * wdn, 10.0f, 1.0f));  // log(a*wdn+0.1)-log(0.1)
        }
        __syncthreads();

        // ---- phase B: pred[b] += acts[b][fi] * Wd[fs+fi][t]
        const int sFirst = segs[0], sLast = segs[FT - 1];
        if (sFirst == sLast) {
            if (sFirst != cur_seg) { flush(cur_seg); cur_seg = sFirst; }
            for (int fi = 0; fi < FT; fi += 4) {
                const float w0 = Wd[(size_t)(fs + fi + 0) * DM + t];
                const float w1 = Wd[(size_t)(fs + fi + 1) * DM + t];
                const float w2 = Wd[(size_t)(fs + fi + 2) * DM + t];
                const float w3 = Wd[(size_t)(fs + fi + 3) * DM + t];
                #pragma unroll
                for (int b = 0; b < BT; ++b) {
                    const float4 a4 = *reinterpret_cast<const float4*>(&acts[b][fi]);
                    pred[b] += a4.x * w0 + a4.y * w1 + a4.z * w2 + a4.w * w3;
                }
            }
        } else {
            // rare: subtile crosses a block boundary — per-feature with checks
            for (int fi = 0; fi < FT; ++fi) {
                const int s = segs[fi];
                if (s != cur_seg) { flush(cur_seg); cur_seg = s; }
                const float w = Wd[(size_t)(fs + fi) * DM + t];
                #pragma unroll
                for (int b = 0; b < BT; ++b) pred[b] += acts[b][fi] * w;
            }
        }
        __syncthreads();
    }
    flush(cur_seg);
    if (my_seg >= 0) atomicAdd(&lds_l1[my_seg], l1_acc);
    atomicAdd(&lds_l0, l0_cnt);
    __syncthreads();
    if (t < NBLK) atomicAdd(&ws[WS_L1 + t], lds_l1[t]);
    if (t == 0) atomicAdd(((unsigned*)ws) + WS_L0, lds_l0);
}

// ---------------- epilogue kernels ----------------

// cumsum over k + squared error; one block per batch row, thread t = dim t
__global__ __launch_bounds__(256) void k_err(const float* __restrict__ x,
                                             const float* __restrict__ bd,
                                             float* ws) {
    const int b = blockIdx.x, t = threadIdx.x;
    const int wave = t >> 6, lane = t & 63;
    const float* preds = ws + WS_PREDS;
    const float scale = ws[WS_SCALE];
    const float xv = x[(size_t)b * DM + t] * scale;
    float p = bd[t];
    __shared__ float lds[NBLK][4];
    for (int k = 0; k < NBLK; ++k) {
        p += preds[(size_t)k * BATCH * DM + (size_t)b * DM + t];
        const float d = p - xv;
        float e = d * d;
        #pragma unroll
        for (int o = 32; o; o >>= 1) e += __shfl_xor(e, o);
        if (lane == 0) lds[k][wave] = e;
    }
    __syncthreads();
    if (t < NBLK) {
        const float s = lds[t][0] + lds[t][1] + lds[t][2] + lds[t][3];
        atomicAdd(&ws[WS_ERR + t], s);
    }
}

__global__ void k_loss(const float* __restrict__ bw,
                       const float* __restrict__ l1s,
                       const float* ws, float* out) {
    float cum = 0.0f, l1 = 0.0f, mse = 0.0f;
    for (int k = 0; k < NBLK; ++k) {
        cum += ws[WS_L1 + k] / (float)BATCH;
        l1 += bw[k] * cum;
        mse += bw[k] * (ws[WS_ERR + k] / (float)BATCH);
    }
    l1 *= (1.0f / NBLK);
    mse *= (1.0f / NBLK);
    const unsigned l0 = ((const unsigned*)ws)[WS_L0];
    const float avg_l0 = (float)l0 / (float)BATCH;
    const float rs = l1s[0] * (avg_l0 < TARGET_L0 ? (1.0f - EPS_CTRL) : (1.0f + EPS_CTRL));
    out[0] = mse + rs * l1;
}

// ---------------- launch ----------------

extern "C" void kernel_launch(void* const* d_in, const int* in_sizes, int n_in,
                              void* d_out, int out_size, void* d_ws, size_t ws_size,
                              hipStream_t stream) {
    const float* x    = (const float*)d_in[0];
    const float* We   = (const float*)d_in[1];
    const float* be   = (const float*)d_in[2];
    const float* Wd   = (const float*)d_in[3];
    const float* bd   = (const float*)d_in[4];
    const float* bw   = (const float*)d_in[5];
    const float* ravg = (const float*)d_in[6];
    const float* l1s  = (const float*)d_in[7];
    const int*   seg  = (const int*)d_in[8];
    float* out = (float*)d_out;
    float* ws  = (float*)d_ws;

    hipMemsetAsync(d_ws, 0, WS_TOTAL_BYTES, stream);
    k_rownorm<<<BATCH / 4, 256, 0, stream>>>(x, ws);
    k_wdn<<<NFEAT / 4, 256, 0, stream>>>(Wd, ws);
    k_scale<<<1, 1, 0, stream>>>(ravg, ws);
    dim3 g(NFEAT / FC, BATCH / BT);
    k_main<<<g, 256, 0, stream>>>(x, We, be, Wd, seg, ws);
    k_err<<<BATCH, 256, 0, stream>>>(x, bd, ws);
    k_loss<<<1, 1, 0, stream>>>(bw, l1s, ws, out);
}

// Round 2
// 372.396 us; speedup vs baseline: 7.7271x; 7.7271x over previous
//
#include <hip/hip_runtime.h>

typedef float  f32x4  __attribute__((ext_vector_type(4)));
typedef __bf16 bf16x8 __attribute__((ext_vector_type(8)));
typedef __bf16 bf16x4 __attribute__((ext_vector_type(4)));
typedef unsigned short u16;

#define BATCH 2048
#define DM    256
#define NFEAT 32768
#define NBLK  8
#define ALPHA_C   0.99f
#define EPS_CTRL  3e-4f
#define TARGET_L0 100.0f

#define BT    64          // batch rows per workgroup
#define FC    2048        // features per chunk
#define MACRO 256         // features per macro-iter
#define NMACRO (FC / MACRO)
#define LROW  264         // LDS row pitch in bf16 elems (528 B; conflict-friendly)

// ---- workspace layout (float offsets for the f32 region) ----
#define WS_RA    0
#define WS_SCALE 1
#define WS_L0    2      // as unsigned
#define WS_L1    4      // 8 floats
#define WS_ERR   16     // 8 floats
#define WS_WDN   256    // 32768 floats
#define WS_PREDS (WS_WDN + NFEAT)                       // 33024
#define PREDS_FLOATS ((size_t)NBLK * BATCH * DM)        // 4194304
#define WS_PRE_BYTES (((size_t)WS_PREDS + PREDS_FLOATS) * 4)   // memset region
#define WET_OFF_BYTES WS_PRE_BYTES                       // bf16 WeT[f][k] 16 MB
#define WDT_OFF_BYTES (WET_OFF_BYTES + (size_t)NFEAT * DM * 2) // bf16 WdT[d][f] 16 MB

static __device__ inline u16 f2b(float f) {
    return __builtin_bit_cast(u16, (__bf16)f);
}

static __device__ inline f32x4 mfma16(bf16x8 a, bf16x8 b, f32x4 c) {
    return __builtin_amdgcn_mfma_f32_16x16x32_bf16(a, b, c, 0, 0, 0);
}

// ---------------- small kernels ----------------

__global__ __launch_bounds__(256) void k_rownorm(const float* __restrict__ x, float* ws) {
    const int wave = threadIdx.x >> 6, lane = threadIdx.x & 63;
    const int row = blockIdx.x * 4 + wave;
    const float4 v = *reinterpret_cast<const float4*>(x + (size_t)row * DM + lane * 4);
    float s = v.x * v.x + v.y * v.y + v.z * v.z + v.w * v.w;
    #pragma unroll
    for (int o = 32; o; o >>= 1) s += __shfl_xor(s, o);
    if (lane == 0) atomicAdd(&ws[WS_RA], sqrtf(s));
}

__global__ __launch_bounds__(256) void k_wdn(const float* __restrict__ Wd, float* ws) {
    const int wave = threadIdx.x >> 6, lane = threadIdx.x & 63;
    const int f = blockIdx.x * 4 + wave;
    const float4 v = *reinterpret_cast<const float4*>(Wd + (size_t)f * DM + lane * 4);
    float s = v.x * v.x + v.y * v.y + v.z * v.z + v.w * v.w;
    #pragma unroll
    for (int o = 32; o; o >>= 1) s += __shfl_xor(s, o);
    if (lane == 0) ws[WS_WDN + f] = sqrtf(s);
}

__global__ void k_scale(const float* __restrict__ ravg, float* ws) {
    float ra = ALPHA_C * ravg[0] + (1.0f - ALPHA_C) * (ws[WS_RA] / (float)BATCH);
    ws[WS_SCALE] = 16.0f / ra;   // sqrt(256) = 16
}

// transpose + bf16 convert: in [R][C] f32 -> out [C][R] bf16. grid (C/64, R/64)
__global__ __launch_bounds__(256) void k_tr(const float* __restrict__ in,
                                            u16* __restrict__ out, int R, int C) {
    __shared__ float tile[64][65];
    const int t = threadIdx.x;
    const int c0 = blockIdx.x * 64, r0 = blockIdx.y * 64;
    #pragma unroll 4
    for (int p = 0; p < 16; ++p) {
        int r = p * 4 + (t >> 6);
        int c = t & 63;
        tile[r][c] = in[(size_t)(r0 + r) * C + c0 + c];
    }
    __syncthreads();
    #pragma unroll 4
    for (int p = 0; p < 16; ++p) {
        int c = p * 4 + (t >> 6);   // out row
        int r = t & 63;
        out[(size_t)(c0 + c) * R + r0 + r] = f2b(tile[r][c]);
    }
}

// ---------------- fused main kernel ----------------
// grid (NFEAT/FC, BATCH/BT), 256 threads = 4 waves.
// encode: wave w owns feats [64w,64w+64) of each macro (4 row-tiles x 4 col-tiles)
// decode: wave w owns out cols [64w,64w+64), rows 0..63; K = features
__global__ __launch_bounds__(256) void k_main(const float* __restrict__ x,
                                              const float* __restrict__ be,
                                              const int* __restrict__ seg,
                                              float* __restrict__ ws,
                                              const u16* __restrict__ WeT,
                                              const u16* __restrict__ WdT) {
    __shared__ __align__(16) u16 xs[BT * LROW];     // xn bf16 [row][k]
    __shared__ __align__(16) u16 acts[BT * LROW];   // acts bf16 [row][f_local]
    __shared__ float lds_l1[NBLK];
    __shared__ unsigned lds_l0;

    const int t = threadIdx.x;
    const int w = t >> 6;
    const int l = t & 63;
    const int l15 = l & 15, lg = l >> 4;
    const int f0 = blockIdx.x * FC;
    const int b0 = blockIdx.y * BT;
    const float scale = ws[WS_SCALE];
    float* preds = ws + WS_PREDS;

    if (t < NBLK) lds_l1[t] = 0.0f;
    if (t == 0) lds_l0 = 0u;

    // stage xn = x*scale as bf16
    #pragma unroll 4
    for (int p = 0; p < 16; ++p) {
        const int row = p * 4 + (t >> 6);
        const int c = (t & 63) * 4;
        const float4 v = *reinterpret_cast<const float4*>(x + (size_t)(b0 + row) * DM + c);
        bf16x4 h;
        h[0] = (__bf16)(v.x * scale); h[1] = (__bf16)(v.y * scale);
        h[2] = (__bf16)(v.z * scale); h[3] = (__bf16)(v.w * scale);
        *reinterpret_cast<bf16x4*>(&xs[row * LROW + c]) = h;
    }
    __syncthreads();

    f32x4 pacc[4][4];   // decode accumulators (persistent)
    #pragma unroll
    for (int i = 0; i < 4; ++i)
        #pragma unroll
        for (int j = 0; j < 4; ++j) pacc[i][j] = (f32x4)0.0f;

    int cur = seg[f0];
    float l1a = 0.0f;
    int myseg = -1;
    unsigned l0c = 0u;

    auto flush = [&](int s) {
        float* pb = preds + (size_t)s * BATCH * DM;
        #pragma unroll
        for (int rt = 0; rt < 4; ++rt)
            #pragma unroll
            for (int ct = 0; ct < 4; ++ct)
                #pragma unroll
                for (int r = 0; r < 4; ++r) {
                    const int row = b0 + 16 * rt + lg * 4 + r;
                    const int col = 64 * w + 16 * ct + l15;
                    atomicAdd(&pb[(size_t)row * DM + col], pacc[rt][ct][r]);
                    pacc[rt][ct][r] = 0.0f;
                }
    };

    for (int ms = 0; ms < NMACRO; ++ms) {
        const int fbase = f0 + ms * MACRO;
        const bool uni = (seg[fbase] == seg[fbase + MACRO - 1]);

        // ---- encode: eacc[rt][ct] over K=256 ----
        f32x4 eacc[4][4];
        #pragma unroll
        for (int i = 0; i < 4; ++i)
            #pragma unroll
            for (int j = 0; j < 4; ++j) eacc[i][j] = (f32x4)0.0f;

        #pragma unroll
        for (int kf = 0; kf < 8; ++kf) {
            bf16x8 a[4], b[4];
            #pragma unroll
            for (int rt = 0; rt < 4; ++rt)
                a[rt] = *reinterpret_cast<const bf16x8*>(&xs[(16 * rt + l15) * LROW + kf * 32 + lg * 8]);
            #pragma unroll
            for (int ct = 0; ct < 4; ++ct) {
                const size_t fg = (size_t)(fbase + 64 * w + 16 * ct + l15);
                b[ct] = *reinterpret_cast<const bf16x8*>(WeT + fg * DM + kf * 32 + lg * 8);
            }
            #pragma unroll
            for (int rt = 0; rt < 4; ++rt)
                #pragma unroll
                for (int ct = 0; ct < 4; ++ct)
                    eacc[rt][ct] = mfma16(a[rt], b[ct], eacc[rt][ct]);
        }

        // ---- epilogue: bias, relu, l1/l0, acts -> LDS bf16 ----
        #pragma unroll
        for (int ct = 0; ct < 4; ++ct) {
            const int fg = fbase + 64 * w + 16 * ct + l15;
            const float bias = be[fg];
            const float wdn10 = ws[WS_WDN + fg] * 10.0f;
            const int s = uni ? seg[fbase] : seg[fg];
            if (s != myseg) {
                if (myseg >= 0) atomicAdd(&lds_l1[myseg], l1a);
                l1a = 0.0f; myseg = s;
            }
            #pragma unroll
            for (int rt = 0; rt < 4; ++rt)
                #pragma unroll
                for (int r = 0; r < 4; ++r) {
                    float a = eacc[rt][ct][r] + bias;
                    a = fmaxf(a, 0.0f);
                    l0c += (a > 0.0f) ? 1u : 0u;
                    l1a += __logf(fmaf(a, wdn10, 1.0f));
                    acts[(16 * rt + lg * 4 + r) * LROW + 64 * w + 16 * ct + l15] = f2b(a);
                }
        }
        __syncthreads();   // acts visible

        // ---- decode: pacc += acts @ WdT^T over this macro's 256 feats ----
        if (uni) {
            const int s = seg[fbase];
            if (s != cur) { flush(cur); cur = s; }
            #pragma unroll
            for (int kf = 0; kf < 8; ++kf) {
                bf16x8 a[4], b[4];
                #pragma unroll
                for (int rt = 0; rt < 4; ++rt)
                    a[rt] = *reinterpret_cast<const bf16x8*>(&acts[(16 * rt + l15) * LROW + kf * 32 + lg * 8]);
                #pragma unroll
                for (int ct = 0; ct < 4; ++ct)
                    b[ct] = *reinterpret_cast<const bf16x8*>(WdT + (size_t)(64 * w + 16 * ct + l15) * NFEAT + fbase + kf * 32 + lg * 8);
                #pragma unroll
                for (int rt = 0; rt < 4; ++rt)
                    #pragma unroll
                    for (int ct = 0; ct < 4; ++ct)
                        pacc[rt][ct] = mfma16(a[rt], b[ct], pacc[rt][ct]);
            }
        } else {
            for (int kf = 0; kf < 8; ++kf) {
                const int W0 = fbase + kf * 32;
                const int s0 = seg[W0], s1 = seg[W0 + 31];
                bf16x8 b[4];
                #pragma unroll
                for (int ct = 0; ct < 4; ++ct)
                    b[ct] = *reinterpret_cast<const bf16x8*>(WdT + (size_t)(64 * w + 16 * ct + l15) * NFEAT + W0 + lg * 8);
                if (s0 == s1) {
                    if (s0 != cur) { flush(cur); cur = s0; }
                    bf16x8 a[4];
                    #pragma unroll
                    for (int rt = 0; rt < 4; ++rt)
                        a[rt] = *reinterpret_cast<const bf16x8*>(&acts[(16 * rt + l15) * LROW + kf * 32 + lg * 8]);
                    #pragma unroll
                    for (int rt = 0; rt < 4; ++rt)
                        #pragma unroll
                        for (int ct = 0; ct < 4; ++ct)
                            pacc[rt][ct] = mfma16(a[rt], b[ct], pacc[rt][ct]);
                } else {
                    int lo = 0;
                    while (lo < 32) {
                        const int s = seg[W0 + lo];
                        int hi = lo + 1;
                        while (hi < 32 && seg[W0 + hi] == s) ++hi;
                        if (s != cur) { flush(cur); cur = s; }
                        bf16x8 a[4];
                        #pragma unroll
                        for (int rt = 0; rt < 4; ++rt) {
                            a[rt] = *reinterpret_cast<const bf16x8*>(&acts[(16 * rt + l15) * LROW + kf * 32 + lg * 8]);
                            #pragma unroll
                            for (int i = 0; i < 8; ++i) {
                                const int kl = lg * 8 + i;
                                if (kl < lo || kl >= hi) a[rt][i] = (__bf16)0.0f;
                            }
                        }
                        #pragma unroll
                        for (int rt = 0; rt < 4; ++rt)
                            #pragma unroll
                            for (int ct = 0; ct < 4; ++ct)
                                pacc[rt][ct] = mfma16(a[rt], b[ct], pacc[rt][ct]);
                        lo = hi;
                    }
                }
            }
        }
        __syncthreads();   // decode reads done before next macro overwrites acts
    }

    flush(cur);
    if (myseg >= 0) atomicAdd(&lds_l1[myseg], l1a);
    atomicAdd(&lds_l0, l0c);
    __syncthreads();
    if (t < NBLK) atomicAdd(&ws[WS_L1 + t], lds_l1[t]);
    if (t == 0) atomicAdd(((unsigned*)ws) + WS_L0, lds_l0);
}

// ---------------- epilogue kernels ----------------

__global__ __launch_bounds__(256) void k_err(const float* __restrict__ x,
                                             const float* __restrict__ bd,
                                             float* ws) {
    const int b = blockIdx.x, t = threadIdx.x;
    const int wave = t >> 6, lane = t & 63;
    const float* preds = ws + WS_PREDS;
    const float scale = ws[WS_SCALE];
    const float xv = x[(size_t)b * DM + t] * scale;
    float p = bd[t];
    __shared__ float lds[NBLK][4];
    for (int k = 0; k < NBLK; ++k) {
        p += preds[(size_t)k * BATCH * DM + (size_t)b * DM + t];
        const float d = p - xv;
        float e = d * d;
        #pragma unroll
        for (int o = 32; o; o >>= 1) e += __shfl_xor(e, o);
        if (lane == 0) lds[k][wave] = e;
    }
    __syncthreads();
    if (t < NBLK) {
        const float s = lds[t][0] + lds[t][1] + lds[t][2] + lds[t][3];
        atomicAdd(&ws[WS_ERR + t], s);
    }
}

__global__ void k_loss(const float* __restrict__ bw,
                       const float* __restrict__ l1s,
                       const float* ws, float* out) {
    float cum = 0.0f, l1 = 0.0f, mse = 0.0f;
    for (int k = 0; k < NBLK; ++k) {
        cum += ws[WS_L1 + k] / (float)BATCH;
        l1 += bw[k] * cum;
        mse += bw[k] * (ws[WS_ERR + k] / (float)BATCH);
    }
    l1 *= (1.0f / NBLK);
    mse *= (1.0f / NBLK);
    const unsigned l0 = ((const unsigned*)ws)[WS_L0];
    const float avg_l0 = (float)l0 / (float)BATCH;
    const float rs = l1s[0] * (avg_l0 < TARGET_L0 ? (1.0f - EPS_CTRL) : (1.0f + EPS_CTRL));
    out[0] = mse + rs * l1;
}

// ---------------- launch ----------------

extern "C" void kernel_launch(void* const* d_in, const int* in_sizes, int n_in,
                              void* d_out, int out_size, void* d_ws, size_t ws_size,
                              hipStream_t stream) {
    const float* x    = (const float*)d_in[0];
    const float* We   = (const float*)d_in[1];
    const float* be   = (const float*)d_in[2];
    const float* Wd   = (const float*)d_in[3];
    const float* bd   = (const float*)d_in[4];
    const float* bw   = (const float*)d_in[5];
    const float* ravg = (const float*)d_in[6];
    const float* l1s  = (const float*)d_in[7];
    const int*   seg  = (const int*)d_in[8];
    float* out = (float*)d_out;
    float* ws  = (float*)d_ws;
    u16* WeT = (u16*)((char*)d_ws + WET_OFF_BYTES);
    u16* WdT = (u16*)((char*)d_ws + WDT_OFF_BYTES);

    hipMemsetAsync(d_ws, 0, WS_PRE_BYTES, stream);
    k_rownorm<<<BATCH / 4, 256, 0, stream>>>(x, ws);
    k_wdn<<<NFEAT / 4, 256, 0, stream>>>(Wd, ws);
    k_tr<<<dim3(NFEAT / 64, DM / 64), 256, 0, stream>>>(We, WeT, DM, NFEAT);
    k_tr<<<dim3(DM / 64, NFEAT / 64), 256, 0, stream>>>(Wd, WdT, NFEAT, DM);
    k_scale<<<1, 1, 0, stream>>>(ravg, ws);
    dim3 g(NFEAT / FC, BATCH / BT);
    k_main<<<g, 256, 0, stream>>>(x, be, seg, ws, WeT, WdT);
    k_err<<<BATCH, 256, 0, stream>>>(x, bd, ws);
    k_loss<<<1, 1, 0, stream>>>(bw, l1s, ws, out);
}